// Round 1
// baseline (279.951 us; speedup 1.0000x reference)
//
#include <hip/hip_runtime.h>
#include <hip/hip_bf16.h>

typedef __bf16 bf16;
typedef __bf16 bf16x8 __attribute__((ext_vector_type(8)));
typedef float  f32x4  __attribute__((ext_vector_type(4)));

#define NEG_BIG (-1e30f)

#define AS1(p) ((const __attribute__((address_space(1))) void*)(p))
#define AS3(p) ((__attribute__((address_space(3))) void*)(p))

// async global->LDS, 16B/lane; dest = wave-uniform base + lane*16 (m104/m108)
__device__ __forceinline__ void stage16(const void* g, void* lds_uniform_base) {
    __builtin_amdgcn_global_load_lds(AS1(g), AS3(lds_uniform_base), 16, 0, 0);
}

__device__ __forceinline__ bf16x8 cvt8(const float* __restrict__ p) {
    bf16x8 r;
#pragma unroll
    for (int i = 0; i < 8; ++i) r[i] = (bf16)p[i];
    return r;
}

// ---------------------------------------------------------------------------
// f32->bf16: x -> xb (ws), Wq/Wk/Wv -> wb (d_out scratch). (R7-proven.)
// ---------------------------------------------------------------------------
__global__ __launch_bounds__(256) void conv_all(
    const float* __restrict__ x,  const float* __restrict__ wq,
    const float* __restrict__ wk, const float* __restrict__ wv,
    bf16* __restrict__ xb, bf16* __restrict__ wb)
{
    const int blk = blockIdx.x;
    const float* src; bf16* dst; size_t off;
    if (blk < 2048)      { src = x;  dst = xb;           off = (size_t)blk * 2048; }
    else if (blk < 2560) { src = wq; dst = wb;           off = (size_t)(blk - 2048) * 2048; }
    else if (blk < 3072) { src = wk; dst = wb + 1048576; off = (size_t)(blk - 2560) * 2048; }
    else                 { src = wv; dst = wb + 2097152; off = (size_t)(blk - 3072) * 2048; }
    const size_t i = off + (size_t)threadIdx.x * 8;
    *(bf16x8*)(dst + i) = cvt8(src + i);
}

// ---------------------------------------------------------------------------
// Fused QKV projection, all-bf16 (R7-proven). y = xb @ Wb.T + b.
// ---------------------------------------------------------------------------
__global__ __launch_bounds__(256) void qkv_gemm(
    const bf16* __restrict__ Xb, const bf16* __restrict__ Wb,
    const float* __restrict__ bq, const float* __restrict__ bk, const float* __restrict__ bv,
    bf16* __restrict__ qo, bf16* __restrict__ ko, bf16* __restrict__ vo)
{
    __shared__ alignas(16) bf16 As[128 * 32];
    __shared__ alignas(16) bf16 Bs[128 * 32];

    const int t    = threadIdx.x;
    const int lane = t & 63, w = t >> 6;
    const int quad = lane >> 4, col = lane & 15;
    const int nt = blockIdx.x;            // 0..23
    const int mt = blockIdx.y;            // 0..31
    const int region = nt >> 3;           // 0=q 1=k 2=v
    const int n0 = (nt & 7) * 128;
    const int m0 = mt * 128;
    const int K  = 1024;

    const bf16*  W    = Wb + (size_t)region * 1048576;
    const float* bias = region == 0 ? bq : (region == 1 ? bk : bv);
    bf16*        out  = region == 0 ? qo : (region == 1 ? ko : vo);
    const float scale = region == 0 ? 0.125f : 1.0f;

    const int wm = (w >> 1) * 64, wn = (w & 1) * 64;
    f32x4 acc[4][4] = {};

    for (int k0 = 0; k0 < K; k0 += 32) {
        __syncthreads();
#pragma unroll
        for (int i = 0; i < 2; ++i) {
            int c = i * 256 + t;
            stage16(Xb + (size_t)(m0 + (c >> 2)) * K + k0 + (c & 3) * 8,
                    As + (i * 256 + w * 64) * 8);
        }
#pragma unroll
        for (int i = 0; i < 2; ++i) {
            int c = i * 256 + t;
            stage16(W + (size_t)(n0 + (c >> 2)) * K + k0 + (c & 3) * 8,
                    Bs + (i * 256 + w * 64) * 8);
        }
        __syncthreads();

        bf16x8 a[4], b[4];
#pragma unroll
        for (int i = 0; i < 4; ++i)
            a[i] = *(const bf16x8*)(As + (wm + i * 16 + col) * 32 + quad * 8);
#pragma unroll
        for (int j = 0; j < 4; ++j)
            b[j] = *(const bf16x8*)(Bs + (wn + j * 16 + col) * 32 + quad * 8);
#pragma unroll
        for (int i = 0; i < 4; ++i)
#pragma unroll
            for (int j = 0; j < 4; ++j)
                acc[i][j] = __builtin_amdgcn_mfma_f32_16x16x32_bf16(a[i], b[j], acc[i][j], 0, 0, 0);
    }

#pragma unroll
    for (int i = 0; i < 4; ++i) {
        const int mbase = m0 + wm + i * 16 + quad * 4;
#pragma unroll
        for (int j = 0; j < 4; ++j) {
            const int n = n0 + wn + j * 16 + col;
            const float bb = bias[n];
            const int h = n >> 6, d = n & 63;
#pragma unroll
            for (int r = 0; r < 4; ++r) {
                const int m  = mbase + r;
                const int b_ = m >> 11, s = m & 2047;
                out[(((size_t)(b_ * 16 + h)) * 2048 + s) * 64 + d] =
                    (bf16)((acc[i][j][r] + bb) * scale);
            }
        }
    }
}

// ---------------------------------------------------------------------------
// Flash attention — R7-proven inner machinery, ONE q-tile per block:
// grid = 16 z-slots x 32 bh = 512 blocks -> 2 blocks/CU co-resident
// (LDS 2x52224 < 160 KiB, 156 VGPR -> >=2 waves/SIMD). z maps to
// qt = z<8 ? 15-z : z-8 so the natural round-robin pairing of block i with
// block i+256 puts (16-z)+(z+1) = 17 kv-stagings on each CU — balanced by
// construction; pairing is a locality heuristic only, never correctness.
// ---------------------------------------------------------------------------
__global__ __launch_bounds__(256) void attn_kernel(
    const bf16* __restrict__ Q, const bf16* __restrict__ Kg,
    const bf16* __restrict__ Vg, bf16* __restrict__ O)
{
    const int t    = threadIdx.x;
    const int lane = t & 63, w = t >> 6;
    const int quad = lane >> 4, col = lane & 15;
    const int bh   = blockIdx.x & 31;
    const int z    = blockIdx.x >> 5;         // 0..15
    const int qt   = (z < 8) ? (15 - z) : (z - 8);
    const int b  = bh >> 4, h = bh & 15;
    const float nslope = -exp2f(-0.5f * (float)(h + 1));

    const bf16* qp = Q  + (size_t)bh * 2048 * 64;
    const bf16* kp = Kg + (size_t)bh * 2048 * 64;
    const bf16* vp = Vg + (size_t)bh * 2048 * 64;

    __shared__ alignas(16) bf16 KP[4 * 32 * 136];   // Ks (9216) ∪ Ps (17408)
    __shared__ alignas(16) bf16 Vt[64 * 136];
    bf16* Ks = KP;
    bf16* Pw = KP + w * (32 * 136);

    const int q0 = qt * 128;

    bf16x8 qa[2][2];
#pragma unroll
    for (int mi = 0; mi < 2; ++mi)
#pragma unroll
        for (int ks = 0; ks < 2; ++ks)
            qa[mi][ks] = *(const bf16x8*)(qp + (size_t)(q0 + w * 32 + mi * 16 + col) * 64
                                          + ks * 32 + quad * 8);

    float mrow[2][4], lrow[2][4];
    f32x4 of[2][4] = {};
#pragma unroll
    for (int mi = 0; mi < 2; ++mi)
#pragma unroll
        for (int r = 0; r < 4; ++r) { mrow[mi][r] = NEG_BIG; lrow[mi][r] = 0.f; }

    for (int kvt = 0; kvt <= qt; ++kvt) {
        const int kv0 = kvt * 128;

        bf16x8 kx[4], va[2], vb_[2];
#pragma unroll
        for (int i = 0; i < 4; ++i) {
            int c = i * 256 + t;
            kx[i] = *(const bf16x8*)(kp + (size_t)(kv0 + (c >> 3)) * 64 + (c & 7) * 8);
        }
#pragma unroll
        for (int i = 0; i < 2; ++i) {
            int c = i * 256 + t;
            va[i]  = *(const bf16x8*)(vp + (size_t)(kv0 + (c >> 3) * 2)     * 64 + (c & 7) * 8);
            vb_[i] = *(const bf16x8*)(vp + (size_t)(kv0 + (c >> 3) * 2 + 1) * 64 + (c & 7) * 8);
        }
        __syncthreads();   // BARRIER1: all waves done with prev KP(Pw)/Vt reads
#pragma unroll
        for (int i = 0; i < 4; ++i) {
            int c = i * 256 + t;
            *(bf16x8*)(Ks + (c >> 3) * 72 + (c & 7) * 8) = kx[i];
        }
#pragma unroll
        for (int i = 0; i < 2; ++i) {
            int c = i * 256 + t;
            int kvp = c >> 3, dc = (c & 7) * 8;
#pragma unroll
            for (int e = 0; e < 8; ++e) {
                Vt[(dc + e) * 136 + kvp * 2]     = va[i][e];
                Vt[(dc + e) * 136 + kvp * 2 + 1] = vb_[i][e];
            }
        }
        __syncthreads();   // BARRIER2: Ks/Vt visible

        // S = Q K^T
        f32x4 sc[2][8];
#pragma unroll
        for (int nj = 0; nj < 8; ++nj) {
            bf16x8 k0f = *(const bf16x8*)(Ks + (nj * 16 + col) * 72 + quad * 8);
            bf16x8 k1f = *(const bf16x8*)(Ks + (nj * 16 + col) * 72 + 32 + quad * 8);
#pragma unroll
            for (int mi = 0; mi < 2; ++mi) {
                f32x4 z2 = {};
                z2 = __builtin_amdgcn_mfma_f32_16x16x32_bf16(qa[mi][0], k0f, z2, 0, 0, 0);
                z2 = __builtin_amdgcn_mfma_f32_16x16x32_bf16(qa[mi][1], k1f, z2, 0, 0, 0);
                sc[mi][nj] = z2;
            }
        }

        const bool diag = (kvt == qt);
#pragma unroll
        for (int mi = 0; mi < 2; ++mi) {
#pragma unroll
            for (int r = 0; r < 4; ++r) {
                const int gi = q0 + w * 32 + mi * 16 + quad * 4 + r;
                float mx = NEG_BIG;
#pragma unroll
                for (int nj = 0; nj < 8; ++nj) {
                    const int gj = kv0 + nj * 16 + col;
                    float val = sc[mi][nj][r] + nslope * (float)(gi - gj);
                    if (diag && gj > gi) val = NEG_BIG;
                    sc[mi][nj][r] = val;
                    mx = fmaxf(mx, val);
                }
#pragma unroll
                for (int off = 1; off < 16; off <<= 1)
                    mx = fmaxf(mx, __shfl_xor(mx, off, 16));
                const float mo = mrow[mi][r];
                const float mn = fmaxf(mo, mx);
                const float alpha = __expf(mo - mn);
                float rs = 0.f;
#pragma unroll
                for (int nj = 0; nj < 8; ++nj) {
                    float p = __expf(sc[mi][nj][r] - mn);
                    sc[mi][nj][r] = p;
                    rs += p;
                }
#pragma unroll
                for (int off = 1; off < 16; off <<= 1)
                    rs += __shfl_xor(rs, off, 16);
                mrow[mi][r] = mn;
                lrow[mi][r] = lrow[mi][r] * alpha + rs;
#pragma unroll
                for (int jd = 0; jd < 4; ++jd) of[mi][jd][r] *= alpha;
            }
        }

        __syncthreads();   // BARRIER3: all waves done reading Ks before P overwrite

        // P: C/D -> A-operand layout via per-wave LDS region (aliases Ks)
#pragma unroll
        for (int mi = 0; mi < 2; ++mi)
#pragma unroll
            for (int nj = 0; nj < 8; ++nj)
#pragma unroll
                for (int r = 0; r < 4; ++r)
                    Pw[(mi * 16 + quad * 4 + r) * 136 + nj * 16 + col] = (bf16)sc[mi][nj][r];

        // O += P V
#pragma unroll
        for (int kk = 0; kk < 4; ++kk) {
            bf16x8 pa0 = *(const bf16x8*)(Pw + (col)      * 136 + kk * 32 + quad * 8);
            bf16x8 pa1 = *(const bf16x8*)(Pw + (16 + col) * 136 + kk * 32 + quad * 8);
#pragma unroll
            for (int jd = 0; jd < 4; ++jd) {
                bf16x8 vbf = *(const bf16x8*)(Vt + (jd * 16 + col) * 136 + kk * 32 + quad * 8);
                of[0][jd] = __builtin_amdgcn_mfma_f32_16x16x32_bf16(pa0, vbf, of[0][jd], 0, 0, 0);
                of[1][jd] = __builtin_amdgcn_mfma_f32_16x16x32_bf16(pa1, vbf, of[1][jd], 0, 0, 0);
            }
        }
    }

    // normalize + write this q-tile's attn output (bf16) to [B,S,E]
#pragma unroll
    for (int mi = 0; mi < 2; ++mi)
#pragma unroll
        for (int r = 0; r < 4; ++r) {
            const int s = q0 + w * 32 + mi * 16 + quad * 4 + r;
            const float inv_l = 1.f / lrow[mi][r];
#pragma unroll
            for (int jd = 0; jd < 4; ++jd) {
                const int e = h * 64 + jd * 16 + col;
                O[((size_t)(b * 2048 + s)) * 1024 + e] = (bf16)(of[mi][jd][r] * inv_l);
            }
        }
}

// ---------------------------------------------------------------------------
// Output projection (R7-proven): A bf16 via stage16; Wo f32 via cvt8.
// ---------------------------------------------------------------------------
__global__ __launch_bounds__(256) void out_gemm(
    const bf16* __restrict__ A, const float* __restrict__ W,
    const float* __restrict__ bias, float* __restrict__ out)
{
    __shared__ alignas(16) bf16 As[128 * 32];
    __shared__ alignas(16) bf16 Bs[128 * 32];

    const int t    = threadIdx.x;
    const int lane = t & 63, w = t >> 6;
    const int quad = lane >> 4, col = lane & 15;
    const int n0 = blockIdx.x * 128;
    const int m0 = blockIdx.y * 128;
    const int K  = 1024;
    const int wm = (w >> 1) * 64, wn = (w & 1) * 64;
    const int r0 = t >> 2, c8 = (t & 3) * 8;
    f32x4 acc[4][4] = {};

    for (int k0 = 0; k0 < K; k0 += 32) {
        bf16x8 bx0 = cvt8(W + (size_t)(n0 + r0)      * K + k0 + c8);
        bf16x8 bx1 = cvt8(W + (size_t)(n0 + 64 + r0) * K + k0 + c8);
        __syncthreads();
#pragma unroll
        for (int i = 0; i < 2; ++i) {
            int c = i * 256 + t;
            stage16(A + (size_t)(m0 + (c >> 2)) * K + k0 + (c & 3) * 8,
                    As + (i * 256 + w * 64) * 8);
        }
        *(bf16x8*)(Bs + r0 * 32 + c8)        = bx0;
        *(bf16x8*)(Bs + (64 + r0) * 32 + c8) = bx1;
        __syncthreads();

        bf16x8 a[4], b[4];
#pragma unroll
        for (int i = 0; i < 4; ++i)
            a[i] = *(const bf16x8*)(As + (wm + i * 16 + col) * 32 + quad * 8);
#pragma unroll
        for (int j = 0; j < 4; ++j)
            b[j] = *(const bf16x8*)(Bs + (wn + j * 16 + col) * 32 + quad * 8);
#pragma unroll
        for (int i = 0; i < 4; ++i)
#pragma unroll
            for (int j = 0; j < 4; ++j)
                acc[i][j] = __builtin_amdgcn_mfma_f32_16x16x32_bf16(a[i], b[j], acc[i][j], 0, 0, 0);
    }

#pragma unroll
    for (int i = 0; i < 4; ++i) {
        const int mbase = m0 + wm + i * 16 + quad * 4;
#pragma unroll
        for (int j = 0; j < 4; ++j) {
            const int n = n0 + wn + j * 16 + col;
            const float bb = bias[n];
#pragma unroll
            for (int r = 0; r < 4; ++r)
                out[(size_t)(mbase + r) * 1024 + n] = acc[i][j][r] + bb;
        }
    }
}

extern "C" void kernel_launch(void* const* d_in, const int* in_sizes, int n_in,
                              void* d_out, int out_size, void* d_ws, size_t ws_size,
                              hipStream_t stream) {
    const float* x  = (const float*)d_in[0];
    const float* Wq = (const float*)d_in[1];
    const float* bq = (const float*)d_in[2];
    const float* Wk = (const float*)d_in[3];
    const float* bk = (const float*)d_in[4];
    const float* Wv = (const float*)d_in[5];
    const float* bv = (const float*)d_in[6];
    const float* Wo = (const float*)d_in[7];
    const float* bo = (const float*)d_in[8];
    float* out = (float*)d_out;

    // ws (32 MB, proven): [xb | q | k | v] bf16; attn output aliases xb.
    bf16* xb  = (bf16*)d_ws;
    bf16* qws = xb  + 4194304;
    bf16* kws = qws + 4194304;
    bf16* vws = kws + 4194304;
    bf16* aws = xb;

    // d_out scratch: bf16 Wq|Wk|Wv (6 MB); dead before out_gemm writes.
    bf16* wb = (bf16*)d_out;

    conv_all<<<dim3(3584), 256, 0, stream>>>(x, Wq, Wk, Wv, xb, wb);
    qkv_gemm<<<dim3(24, 32), 256, 0, stream>>>(xb, wb, bq, bk, bv, qws, kws, vws);
    attn_kernel<<<dim3(512), 256, 0, stream>>>(qws, kws, vws, aws);
    out_gemm<<<dim3(8, 32), 256, 0, stream>>>(aws, Wo, bo, out);
}

// Round 2
// 216.909 us; speedup vs baseline: 1.2906x; 1.2906x over previous
//
#include <hip/hip_runtime.h>
#include <hip/hip_bf16.h>

typedef __bf16 bf16;
typedef __bf16 bf16x4 __attribute__((ext_vector_type(4)));
typedef __bf16 bf16x8 __attribute__((ext_vector_type(8)));
typedef float  f32x4  __attribute__((ext_vector_type(4)));

#define NEG_BIG (-1e30f)
#define LOG2E 1.44269504088896340736f

#define AS1(p) ((const __attribute__((address_space(1))) void*)(p))
#define AS3(p) ((__attribute__((address_space(3))) void*)(p))

// async global->LDS, 16B/lane; dest = wave-uniform base + lane*16 (m104/m108)
__device__ __forceinline__ void stage16(const void* g, void* lds_uniform_base) {
    __builtin_amdgcn_global_load_lds(AS1(g), AS3(lds_uniform_base), 16, 0, 0);
}

__device__ __forceinline__ bf16x8 cvt8(const float* __restrict__ p) {
    bf16x8 r;
#pragma unroll
    for (int i = 0; i < 8; ++i) r[i] = (bf16)p[i];
    return r;
}

// ---- DPP butterfly reduce over 16 consecutive lanes (pure VALU, no LDS) ----
// steps: quad_perm xor1 (0xB1), quad_perm xor2 (0x4E), row_half_mirror (xor7,
// 0x141), row_mirror (xor15, 0x140). All stay within the 16-lane DPP row.
template <int CTRL>
__device__ __forceinline__ float dpp_max_step(float x) {
    int v = __builtin_bit_cast(int, x);
    int s = __builtin_amdgcn_update_dpp(v, v, CTRL, 0xF, 0xF, true);
    return fmaxf(x, __builtin_bit_cast(float, s));
}
template <int CTRL>
__device__ __forceinline__ float dpp_add_step(float x) {
    int v = __builtin_bit_cast(int, x);
    int s = __builtin_amdgcn_update_dpp(v, v, CTRL, 0xF, 0xF, true);
    return x + __builtin_bit_cast(float, s);
}
__device__ __forceinline__ float red16_max(float x) {
    x = dpp_max_step<0xB1>(x);
    x = dpp_max_step<0x4E>(x);
    x = dpp_max_step<0x141>(x);
    x = dpp_max_step<0x140>(x);
    return x;
}
__device__ __forceinline__ float red16_sum(float x) {
    x = dpp_add_step<0xB1>(x);
    x = dpp_add_step<0x4E>(x);
    x = dpp_add_step<0x141>(x);
    x = dpp_add_step<0x140>(x);
    return x;
}

#if __has_builtin(__builtin_amdgcn_exp2f)
#define EXP2F(x) __builtin_amdgcn_exp2f(x)
#else
#define EXP2F(x) exp2f(x)
#endif

// ---------------------------------------------------------------------------
// f32->bf16: x -> xb (ws), Wq/Wk/Wv -> wb (d_out scratch). (R7-proven.)
// ---------------------------------------------------------------------------
__global__ __launch_bounds__(256) void conv_all(
    const float* __restrict__ x,  const float* __restrict__ wq,
    const float* __restrict__ wk, const float* __restrict__ wv,
    bf16* __restrict__ xb, bf16* __restrict__ wb)
{
    const int blk = blockIdx.x;
    const float* src; bf16* dst; size_t off;
    if (blk < 2048)      { src = x;  dst = xb;           off = (size_t)blk * 2048; }
    else if (blk < 2560) { src = wq; dst = wb;           off = (size_t)(blk - 2048) * 2048; }
    else if (blk < 3072) { src = wk; dst = wb + 1048576; off = (size_t)(blk - 2560) * 2048; }
    else                 { src = wv; dst = wb + 2097152; off = (size_t)(blk - 3072) * 2048; }
    const size_t i = off + (size_t)threadIdx.x * 8;
    *(bf16x8*)(dst + i) = cvt8(src + i);
}

// ---------------------------------------------------------------------------
// Fused QKV projection, all-bf16 (R7-proven core). y = xb @ Wb.T + b.
// Q is scaled by 0.125*log2e (exp2-domain softmax). V is written TRANSPOSED:
// V^T[bh][64][2048] so attn can stage it with global_load_lds (no transpose).
// ---------------------------------------------------------------------------
__global__ __launch_bounds__(256) void qkv_gemm(
    const bf16* __restrict__ Xb, const bf16* __restrict__ Wb,
    const float* __restrict__ bq, const float* __restrict__ bk, const float* __restrict__ bv,
    bf16* __restrict__ qo, bf16* __restrict__ ko, bf16* __restrict__ vo)
{
    __shared__ alignas(16) bf16 As[128 * 32];
    __shared__ alignas(16) bf16 Bs[128 * 32];

    const int t    = threadIdx.x;
    const int lane = t & 63, w = t >> 6;
    const int quad = lane >> 4, col = lane & 15;
    const int nt = blockIdx.x;            // 0..23
    const int mt = blockIdx.y;            // 0..31
    const int region = nt >> 3;           // 0=q 1=k 2=v
    const int n0 = (nt & 7) * 128;
    const int m0 = mt * 128;
    const int K  = 1024;

    const bf16*  W    = Wb + (size_t)region * 1048576;
    const float* bias = region == 0 ? bq : (region == 1 ? bk : bv);

    const int wm = (w >> 1) * 64, wn = (w & 1) * 64;
    f32x4 acc[4][4] = {};

    for (int k0 = 0; k0 < K; k0 += 32) {
        __syncthreads();
#pragma unroll
        for (int i = 0; i < 2; ++i) {
            int c = i * 256 + t;
            stage16(Xb + (size_t)(m0 + (c >> 2)) * K + k0 + (c & 3) * 8,
                    As + (i * 256 + w * 64) * 8);
        }
#pragma unroll
        for (int i = 0; i < 2; ++i) {
            int c = i * 256 + t;
            stage16(W + (size_t)(n0 + (c >> 2)) * K + k0 + (c & 3) * 8,
                    Bs + (i * 256 + w * 64) * 8);
        }
        __syncthreads();

        bf16x8 a[4], b[4];
#pragma unroll
        for (int i = 0; i < 4; ++i)
            a[i] = *(const bf16x8*)(As + (wm + i * 16 + col) * 32 + quad * 8);
#pragma unroll
        for (int j = 0; j < 4; ++j)
            b[j] = *(const bf16x8*)(Bs + (wn + j * 16 + col) * 32 + quad * 8);
#pragma unroll
        for (int i = 0; i < 4; ++i)
#pragma unroll
            for (int j = 0; j < 4; ++j)
                acc[i][j] = __builtin_amdgcn_mfma_f32_16x16x32_bf16(a[i], b[j], acc[i][j], 0, 0, 0);
    }

    if (region == 2) {
        // V^T epilogue: rows d = n&63, cols s (contiguous in r) -> packed 8B stores
#pragma unroll
        for (int i = 0; i < 4; ++i) {
            const int mbase = m0 + wm + i * 16 + quad * 4;
            const int b_ = mbase >> 11, s = mbase & 2047;
#pragma unroll
            for (int j = 0; j < 4; ++j) {
                const int n = n0 + wn + j * 16 + col;
                const float bb = bias[n];
                const int h = n >> 6, d = n & 63;
                bf16x4 pk;
#pragma unroll
                for (int r = 0; r < 4; ++r) pk[r] = (bf16)(acc[i][j][r] + bb);
                *(bf16x4*)(vo + ((size_t)(b_ * 16 + h) * 64 + d) * 2048 + s) = pk;
            }
        }
    } else {
        bf16* out = region == 0 ? qo : ko;
        const float scale = region == 0 ? (0.125f * LOG2E) : 1.0f;
#pragma unroll
        for (int i = 0; i < 4; ++i) {
            const int mbase = m0 + wm + i * 16 + quad * 4;
#pragma unroll
            for (int j = 0; j < 4; ++j) {
                const int n = n0 + wn + j * 16 + col;
                const float bb = bias[n];
                const int h = n >> 6, d = n & 63;
#pragma unroll
                for (int r = 0; r < 4; ++r) {
                    const int m  = mbase + r;
                    const int b_ = m >> 11, s = m & 2047;
                    out[(((size_t)(b_ * 16 + h)) * 2048 + s) * 64 + d] =
                        (bf16)((acc[i][j][r] + bb) * scale);
                }
            }
        }
    }
}

// ---------------------------------------------------------------------------
// Flash attention — equal-work pairing (R0-proven grid: 8 pairs x 32 bh = 256
// blocks, (16-pair)+(pair+1) = 17 kv-stagings per block).  New inner loop:
//   * K and V^T staged via global_load_lds with pre-swizzled global source,
//     XOR-swizzled b128 reads (both-sides swizzle, rule 21) — zero ds_writes,
//     conflict-free reads.
//   * Double-buffered K/V with prefetch issued at iteration top; ONE barrier
//     per kv-step (P region is per-wave & private -> no P barriers).
//   * Softmax reduces via DPP (no ds_swizzle), exp2-domain, hoisted ALiBi.
// ---------------------------------------------------------------------------
__global__ __launch_bounds__(256) void attn_kernel(
    const bf16* __restrict__ Q, const bf16* __restrict__ Kg,
    const bf16* __restrict__ Vt, bf16* __restrict__ O)
{
    const int t    = threadIdx.x;
    const int lane = t & 63, w = t >> 6;
    const int quad = lane >> 4, col = lane & 15;
    const int bh   = blockIdx.x & 31;
    const int pair = blockIdx.x >> 5;         // 0..7
    const int b  = bh >> 4, h = bh & 15;
    const float nslope = -EXP2F(-0.5f * (float)(h + 1)) * LOG2E;

    const bf16* qp  = Q  + (size_t)bh * 2048 * 64;
    const bf16* kp  = Kg + (size_t)bh * 2048 * 64;
    const bf16* vtp = Vt + (size_t)bh * 64 * 2048;   // V^T: [64][2048]

    // K tile: [128 kv][64 d], row=128B, chunk(16B) index d8 xor'd with (kv&7)
    // V tile: [64 d][128 kv], row=256B, chunk index kv8 xor'd with (d&7)
    __shared__ alignas(16) bf16 Kbuf[2][128 * 64];
    __shared__ alignas(16) bf16 Vbuf[2][64 * 128];
    __shared__ alignas(16) bf16 Ps[4 * 32 * 136];
    bf16* Pw = Ps + w * (32 * 136);

    for (int pass = 0; pass < 2; ++pass) {
        const int qt = pass == 0 ? (15 - pair) : pair;
        const int q0 = qt * 128;

        bf16x8 qa[2][2];
#pragma unroll
        for (int mi = 0; mi < 2; ++mi)
#pragma unroll
            for (int ks = 0; ks < 2; ++ks)
                qa[mi][ks] = *(const bf16x8*)(qp + (size_t)(q0 + w * 32 + mi * 16 + col) * 64
                                              + ks * 32 + quad * 8);

        float mrow[2][4], lrow[2][4];
        f32x4 of[2][4] = {};
        float bi[2][4];
        int   gi0[2];
#pragma unroll
        for (int mi = 0; mi < 2; ++mi) {
            gi0[mi] = q0 + w * 32 + mi * 16 + quad * 4;
#pragma unroll
            for (int r = 0; r < 4; ++r) {
                mrow[mi][r] = NEG_BIG; lrow[mi][r] = 0.f;
                bi[mi][r] = nslope * (float)(gi0[mi] + r);
            }
        }

        // prologue: stage kv-tile 0 into buffer 0
        {
#pragma unroll
            for (int i = 0; i < 4; ++i) {
                int c = i * 256 + t;
                int row = c >> 3, j8 = (c & 7) ^ (row & 7);
                stage16(kp + (size_t)row * 64 + j8 * 8, Kbuf[0] + (i * 256 + w * 64) * 8);
            }
#pragma unroll
            for (int i = 0; i < 4; ++i) {
                int c = i * 256 + t;
                int d = c >> 4, j8 = (c & 15) ^ (d & 7);
                stage16(vtp + (size_t)d * 2048 + j8 * 8, Vbuf[0] + (i * 256 + w * 64) * 8);
            }
        }
        __syncthreads();

        for (int kvt = 0; kvt <= qt; ++kvt) {
            const int kv0 = kvt * 128;
            const bf16* Kb = Kbuf[kvt & 1];
            const bf16* Vb = Vbuf[kvt & 1];

            // prefetch next tile into the other buffer (async; drained by the
            // end-of-iteration barrier)
            if (kvt < qt) {
                bf16* Kn = Kbuf[(kvt & 1) ^ 1];
                bf16* Vn = Vbuf[(kvt & 1) ^ 1];
                const int nv0 = kv0 + 128;
#pragma unroll
                for (int i = 0; i < 4; ++i) {
                    int c = i * 256 + t;
                    int row = c >> 3, j8 = (c & 7) ^ (row & 7);
                    stage16(kp + (size_t)(nv0 + row) * 64 + j8 * 8, Kn + (i * 256 + w * 64) * 8);
                }
#pragma unroll
                for (int i = 0; i < 4; ++i) {
                    int c = i * 256 + t;
                    int d = c >> 4, j8 = (c & 15) ^ (d & 7);
                    stage16(vtp + (size_t)d * 2048 + nv0 + j8 * 8, Vn + (i * 256 + w * 64) * 8);
                }
            }

            // S = Q K^T  (swizzled K reads: chunk = (quad + 4*ks) ^ (row&7))
            f32x4 sc[2][8];
#pragma unroll
            for (int nj = 0; nj < 8; ++nj) {
                const int row = nj * 16 + col;
                const bf16* kb = Kb + row * 64;
                const int rx = row & 7;
                bf16x8 k0f = *(const bf16x8*)(kb + (quad ^ rx) * 8);
                bf16x8 k1f = *(const bf16x8*)(kb + ((quad + 4) ^ rx) * 8);
#pragma unroll
                for (int mi = 0; mi < 2; ++mi) {
                    f32x4 z = {};
                    z = __builtin_amdgcn_mfma_f32_16x16x32_bf16(qa[mi][0], k0f, z, 0, 0, 0);
                    z = __builtin_amdgcn_mfma_f32_16x16x32_bf16(qa[mi][1], k1f, z, 0, 0, 0);
                    sc[mi][nj] = z;
                }
            }

            // softmax (exp2-domain, DPP reduces, hoisted ALiBi)
            const bool diag = (kvt == qt);
            float bj[8];
#pragma unroll
            for (int nj = 0; nj < 8; ++nj)
                bj[nj] = nslope * (float)(kv0 + nj * 16 + col);

#pragma unroll
            for (int mi = 0; mi < 2; ++mi) {
#pragma unroll
                for (int r = 0; r < 4; ++r) {
#pragma unroll
                    for (int nj = 0; nj < 8; ++nj)
                        sc[mi][nj][r] += bi[mi][r] - bj[nj];
                    if (diag) {
                        const int gi = gi0[mi] + r;
#pragma unroll
                        for (int nj = 0; nj < 8; ++nj)
                            if (kv0 + nj * 16 + col > gi) sc[mi][nj][r] = NEG_BIG;
                    }
                    float mx = sc[mi][0][r];
#pragma unroll
                    for (int nj = 1; nj < 8; ++nj) mx = fmaxf(mx, sc[mi][nj][r]);
                    mx = red16_max(mx);
                    const float mo = mrow[mi][r];
                    const float mn = fmaxf(mo, mx);
                    const float alpha = EXP2F(mo - mn);
                    float rs = 0.f;
#pragma unroll
                    for (int nj = 0; nj < 8; ++nj) {
                        float p = EXP2F(sc[mi][nj][r] - mn);
                        sc[mi][nj][r] = p;
                        rs += p;
                    }
                    rs = red16_sum(rs);
                    mrow[mi][r] = mn;
                    lrow[mi][r] = lrow[mi][r] * alpha + rs;
#pragma unroll
                    for (int jd = 0; jd < 4; ++jd) of[mi][jd][r] *= alpha;
                }
            }

            // P: C/D -> A-operand layout via private per-wave LDS region
            // (no barrier needed: only this wave writes & reads Pw)
#pragma unroll
            for (int mi = 0; mi < 2; ++mi)
#pragma unroll
                for (int nj = 0; nj < 8; ++nj)
#pragma unroll
                    for (int r = 0; r < 4; ++r)
                        Pw[(mi * 16 + quad * 4 + r) * 136 + nj * 16 + col] = (bf16)sc[mi][nj][r];

            // O += P V  (swizzled V reads: chunk = (kk*4+quad) ^ (d&7))
#pragma unroll
            for (int kk = 0; kk < 4; ++kk) {
                bf16x8 pa0 = *(const bf16x8*)(Pw + (col)      * 136 + kk * 32 + quad * 8);
                bf16x8 pa1 = *(const bf16x8*)(Pw + (16 + col) * 136 + kk * 32 + quad * 8);
#pragma unroll
                for (int jd = 0; jd < 4; ++jd) {
                    const int rd = jd * 16 + col;
                    bf16x8 vbf = *(const bf16x8*)(Vb + rd * 128 + (((kk * 4 + quad) ^ (rd & 7)) * 8));
                    of[0][jd] = __builtin_amdgcn_mfma_f32_16x16x32_bf16(pa0, vbf, of[0][jd], 0, 0, 0);
                    of[1][jd] = __builtin_amdgcn_mfma_f32_16x16x32_bf16(pa1, vbf, of[1][jd], 0, 0, 0);
                }
            }

            // ONE barrier: (a) everyone done reading Kb/Vb before next-iter
            // overwrite, (b) vmcnt drain -> prefetched tile visible next iter.
            __syncthreads();
        }

        // normalize + write this q-tile's attn output (bf16) to [B,S,E]
#pragma unroll
        for (int mi = 0; mi < 2; ++mi)
#pragma unroll
            for (int r = 0; r < 4; ++r) {
                const int s = q0 + w * 32 + mi * 16 + quad * 4 + r;
                const float inv_l = 1.f / lrow[mi][r];
#pragma unroll
                for (int jd = 0; jd < 4; ++jd) {
                    const int e = h * 64 + jd * 16 + col;
                    O[((size_t)(b * 2048 + s)) * 1024 + e] = (bf16)(of[mi][jd][r] * inv_l);
                }
            }
    }
}

// ---------------------------------------------------------------------------
// Output projection (R7-proven): A bf16 via stage16; Wo f32 via cvt8.
// ---------------------------------------------------------------------------
__global__ __launch_bounds__(256) void out_gemm(
    const bf16* __restrict__ A, const float* __restrict__ W,
    const float* __restrict__ bias, float* __restrict__ out)
{
    __shared__ alignas(16) bf16 As[128 * 32];
    __shared__ alignas(16) bf16 Bs[128 * 32];

    const int t    = threadIdx.x;
    const int lane = t & 63, w = t >> 6;
    const int quad = lane >> 4, col = lane & 15;
    const int n0 = blockIdx.x * 128;
    const int m0 = blockIdx.y * 128;
    const int K  = 1024;
    const int wm = (w >> 1) * 64, wn = (w & 1) * 64;
    const int r0 = t >> 2, c8 = (t & 3) * 8;
    f32x4 acc[4][4] = {};

    for (int k0 = 0; k0 < K; k0 += 32) {
        bf16x8 bx0 = cvt8(W + (size_t)(n0 + r0)      * K + k0 + c8);
        bf16x8 bx1 = cvt8(W + (size_t)(n0 + 64 + r0) * K + k0 + c8);
        __syncthreads();
#pragma unroll
        for (int i = 0; i < 2; ++i) {
            int c = i * 256 + t;
            stage16(A + (size_t)(m0 + (c >> 2)) * K + k0 + (c & 3) * 8,
                    As + (i * 256 + w * 64) * 8);
        }
        *(bf16x8*)(Bs + r0 * 32 + c8)        = bx0;
        *(bf16x8*)(Bs + (64 + r0) * 32 + c8) = bx1;
        __syncthreads();

        bf16x8 a[4], b[4];
#pragma unroll
        for (int i = 0; i < 4; ++i)
            a[i] = *(const bf16x8*)(As + (wm + i * 16 + col) * 32 + quad * 8);
#pragma unroll
        for (int j = 0; j < 4; ++j)
            b[j] = *(const bf16x8*)(Bs + (wn + j * 16 + col) * 32 + quad * 8);
#pragma unroll
        for (int i = 0; i < 4; ++i)
#pragma unroll
            for (int j = 0; j < 4; ++j)
                acc[i][j] = __builtin_amdgcn_mfma_f32_16x16x32_bf16(a[i], b[j], acc[i][j], 0, 0, 0);
    }

#pragma unroll
    for (int i = 0; i < 4; ++i) {
        const int mbase = m0 + wm + i * 16 + quad * 4;
#pragma unroll
        for (int j = 0; j < 4; ++j) {
            const int n = n0 + wn + j * 16 + col;
            const float bb = bias[n];
#pragma unroll
            for (int r = 0; r < 4; ++r)
                out[(size_t)(mbase + r) * 1024 + n] = acc[i][j][r] + bb;
        }
    }
}

extern "C" void kernel_launch(void* const* d_in, const int* in_sizes, int n_in,
                              void* d_out, int out_size, void* d_ws, size_t ws_size,
                              hipStream_t stream) {
    const float* x  = (const float*)d_in[0];
    const float* Wq = (const float*)d_in[1];
    const float* bq = (const float*)d_in[2];
    const float* Wk = (const float*)d_in[3];
    const float* bk = (const float*)d_in[4];
    const float* Wv = (const float*)d_in[5];
    const float* bv = (const float*)d_in[6];
    const float* Wo = (const float*)d_in[7];
    const float* bo = (const float*)d_in[8];
    float* out = (float*)d_out;

    // ws (32 MB, proven): [xb | q | k | v^T] bf16; attn output aliases xb.
    bf16* xb  = (bf16*)d_ws;
    bf16* qws = xb  + 4194304;
    bf16* kws = qws + 4194304;
    bf16* vws = kws + 4194304;
    bf16* aws = xb;

    // d_out scratch: bf16 Wq|Wk|Wv (6 MB); dead before out_gemm writes.
    bf16* wb = (bf16*)d_out;

    conv_all<<<dim3(3584), 256, 0, stream>>>(x, Wq, Wk, Wv, xb, wb);
    qkv_gemm<<<dim3(24, 32), 256, 0, stream>>>(xb, wb, bq, bk, bv, qws, kws, vws);
    attn_kernel<<<dim3(256), 256, 0, stream>>>(qws, kws, vws, aws);
    out_gemm<<<dim3(8, 32), 256, 0, stream>>>(aws, Wo, bo, out);
}

// Round 3
// 210.677 us; speedup vs baseline: 1.3288x; 1.0296x over previous
//
#include <hip/hip_runtime.h>
#include <hip/hip_bf16.h>

typedef __bf16 bf16;
typedef __bf16 bf16x4 __attribute__((ext_vector_type(4)));
typedef __bf16 bf16x8 __attribute__((ext_vector_type(8)));
typedef float  f32x4  __attribute__((ext_vector_type(4)));

#define NEG_BIG (-1e30f)
#define LOG2E 1.44269504088896340736f

#define AS1(p) ((const __attribute__((address_space(1))) void*)(p))
#define AS3(p) ((__attribute__((address_space(3))) void*)(p))

// async global->LDS, 16B/lane; dest = wave-uniform base + lane*16 (m104/m108)
__device__ __forceinline__ void stage16(const void* g, void* lds_uniform_base) {
    __builtin_amdgcn_global_load_lds(AS1(g), AS3(lds_uniform_base), 16, 0, 0);
}

__device__ __forceinline__ bf16x8 cvt8(const float* __restrict__ p) {
    bf16x8 r;
#pragma unroll
    for (int i = 0; i < 8; ++i) r[i] = (bf16)p[i];
    return r;
}

// ---- DPP butterfly reduce over 16 consecutive lanes (pure VALU, no LDS) ----
template <int CTRL>
__device__ __forceinline__ float dpp_max_step(float x) {
    int v = __builtin_bit_cast(int, x);
    int s = __builtin_amdgcn_update_dpp(v, v, CTRL, 0xF, 0xF, true);
    return fmaxf(x, __builtin_bit_cast(float, s));
}
template <int CTRL>
__device__ __forceinline__ float dpp_add_step(float x) {
    int v = __builtin_bit_cast(int, x);
    int s = __builtin_amdgcn_update_dpp(v, v, CTRL, 0xF, 0xF, true);
    return x + __builtin_bit_cast(float, s);
}
__device__ __forceinline__ float red16_max(float x) {
    x = dpp_max_step<0xB1>(x);
    x = dpp_max_step<0x4E>(x);
    x = dpp_max_step<0x141>(x);
    x = dpp_max_step<0x140>(x);
    return x;
}
__device__ __forceinline__ float red16_sum(float x) {
    x = dpp_add_step<0xB1>(x);
    x = dpp_add_step<0x4E>(x);
    x = dpp_add_step<0x141>(x);
    x = dpp_add_step<0x140>(x);
    return x;
}

#if __has_builtin(__builtin_amdgcn_exp2f)
#define EXP2F(x) __builtin_amdgcn_exp2f(x)
#else
#define EXP2F(x) exp2f(x)
#endif

// ---------------------------------------------------------------------------
// f32->bf16: x -> xb (ws), Wq/Wk/Wv -> wb (d_out scratch). (R7-proven.)
// ---------------------------------------------------------------------------
__global__ __launch_bounds__(256) void conv_all(
    const float* __restrict__ x,  const float* __restrict__ wq,
    const float* __restrict__ wk, const float* __restrict__ wv,
    bf16* __restrict__ xb, bf16* __restrict__ wb)
{
    const int blk = blockIdx.x;
    const float* src; bf16* dst; size_t off;
    if (blk < 2048)      { src = x;  dst = xb;           off = (size_t)blk * 2048; }
    else if (blk < 2560) { src = wq; dst = wb;           off = (size_t)(blk - 2048) * 2048; }
    else if (blk < 3072) { src = wk; dst = wb + 1048576; off = (size_t)(blk - 2560) * 2048; }
    else                 { src = wv; dst = wb + 2097152; off = (size_t)(blk - 3072) * 2048; }
    const size_t i = off + (size_t)threadIdx.x * 8;
    *(bf16x8*)(dst + i) = cvt8(src + i);
}

// ---------------------------------------------------------------------------
// Fused QKV projection, all-bf16 (R7-proven core). y = xb @ Wb.T + b.
// Q is scaled by 0.125*log2e (exp2-domain softmax). V is written TRANSPOSED:
// V^T[bh][64][2048] so attn can stage it with global_load_lds (no transpose).
// ---------------------------------------------------------------------------
__global__ __launch_bounds__(256) void qkv_gemm(
    const bf16* __restrict__ Xb, const bf16* __restrict__ Wb,
    const float* __restrict__ bq, const float* __restrict__ bk, const float* __restrict__ bv,
    bf16* __restrict__ qo, bf16* __restrict__ ko, bf16* __restrict__ vo)
{
    __shared__ alignas(16) bf16 As[128 * 32];
    __shared__ alignas(16) bf16 Bs[128 * 32];

    const int t    = threadIdx.x;
    const int lane = t & 63, w = t >> 6;
    const int quad = lane >> 4, col = lane & 15;
    const int nt = blockIdx.x;            // 0..23
    const int mt = blockIdx.y;            // 0..31
    const int region = nt >> 3;           // 0=q 1=k 2=v
    const int n0 = (nt & 7) * 128;
    const int m0 = mt * 128;
    const int K  = 1024;

    const bf16*  W    = Wb + (size_t)region * 1048576;
    const float* bias = region == 0 ? bq : (region == 1 ? bk : bv);

    const int wm = (w >> 1) * 64, wn = (w & 1) * 64;
    f32x4 acc[4][4] = {};

    for (int k0 = 0; k0 < K; k0 += 32) {
        __syncthreads();
#pragma unroll
        for (int i = 0; i < 2; ++i) {
            int c = i * 256 + t;
            stage16(Xb + (size_t)(m0 + (c >> 2)) * K + k0 + (c & 3) * 8,
                    As + (i * 256 + w * 64) * 8);
        }
#pragma unroll
        for (int i = 0; i < 2; ++i) {
            int c = i * 256 + t;
            stage16(W + (size_t)(n0 + (c >> 2)) * K + k0 + (c & 3) * 8,
                    Bs + (i * 256 + w * 64) * 8);
        }
        __syncthreads();

        bf16x8 a[4], b[4];
#pragma unroll
        for (int i = 0; i < 4; ++i)
            a[i] = *(const bf16x8*)(As + (wm + i * 16 + col) * 32 + quad * 8);
#pragma unroll
        for (int j = 0; j < 4; ++j)
            b[j] = *(const bf16x8*)(Bs + (wn + j * 16 + col) * 32 + quad * 8);
#pragma unroll
        for (int i = 0; i < 4; ++i)
#pragma unroll
            for (int j = 0; j < 4; ++j)
                acc[i][j] = __builtin_amdgcn_mfma_f32_16x16x32_bf16(a[i], b[j], acc[i][j], 0, 0, 0);
    }

    if (region == 2) {
        // V^T epilogue: rows d = n&63, cols s (contiguous in r) -> packed 8B stores
#pragma unroll
        for (int i = 0; i < 4; ++i) {
            const int mbase = m0 + wm + i * 16 + quad * 4;
            const int b_ = mbase >> 11, s = mbase & 2047;
#pragma unroll
            for (int j = 0; j < 4; ++j) {
                const int n = n0 + wn + j * 16 + col;
                const float bb = bias[n];
                const int h = n >> 6, d = n & 63;
                bf16x4 pk;
#pragma unroll
                for (int r = 0; r < 4; ++r) pk[r] = (bf16)(acc[i][j][r] + bb);
                *(bf16x4*)(vo + ((size_t)(b_ * 16 + h) * 64 + d) * 2048 + s) = pk;
            }
        }
    } else {
        bf16* out = region == 0 ? qo : ko;
        const float scale = region == 0 ? (0.125f * LOG2E) : 1.0f;
#pragma unroll
        for (int i = 0; i < 4; ++i) {
            const int mbase = m0 + wm + i * 16 + quad * 4;
#pragma unroll
            for (int j = 0; j < 4; ++j) {
                const int n = n0 + wn + j * 16 + col;
                const float bb = bias[n];
                const int h = n >> 6, d = n & 63;
#pragma unroll
                for (int r = 0; r < 4; ++r) {
                    const int m  = mbase + r;
                    const int b_ = m >> 11, s = m & 2047;
                    out[(((size_t)(b_ * 16 + h)) * 2048 + s) * 64 + d] =
                        (bf16)((acc[i][j][r] + bb) * scale);
                }
            }
        }
    }
}

// ---------------------------------------------------------------------------
// Flash attention — equal-work pairing (256 blocks), now 512 threads = 8
// waves/block -> 2 waves/SIMD (was 1): wave A's softmax dependency stalls
// fill with wave B's MFMA/DS issue. Each wave owns 16 q-rows. All R2 inner
// machinery kept: stage16 K/V with both-sides XOR swizzle, double-buffer,
// 1 barrier/step, DPP softmax reduces, exp2 domain, hoisted ALiBi.
// LDS: 32K (K dbuf) + 32K (V dbuf) + 34816 (P, per-wave 16x136) = 100352 B.
// ---------------------------------------------------------------------------
__global__ __launch_bounds__(512) void attn_kernel(
    const bf16* __restrict__ Q, const bf16* __restrict__ Kg,
    const bf16* __restrict__ Vt, bf16* __restrict__ O)
{
    const int t    = threadIdx.x;
    const int lane = t & 63, w = t >> 6;      // w = 0..7
    const int quad = lane >> 4, col = lane & 15;
    const int bh   = blockIdx.x & 31;
    const int pair = blockIdx.x >> 5;         // 0..7
    const int b  = bh >> 4, h = bh & 15;
    const float nslope = -EXP2F(-0.5f * (float)(h + 1)) * LOG2E;

    const bf16* qp  = Q  + (size_t)bh * 2048 * 64;
    const bf16* kp  = Kg + (size_t)bh * 2048 * 64;
    const bf16* vtp = Vt + (size_t)bh * 64 * 2048;   // V^T: [64][2048]

    __shared__ alignas(16) bf16 Kbuf[2][128 * 64];
    __shared__ alignas(16) bf16 Vbuf[2][64 * 128];
    __shared__ alignas(16) bf16 Ps[8 * 16 * 136];
    bf16* Pw = Ps + w * (16 * 136);

    for (int pass = 0; pass < 2; ++pass) {
        const int qt = pass == 0 ? (15 - pair) : pair;
        const int q0 = qt * 128;

        bf16x8 qa[2];
#pragma unroll
        for (int ks = 0; ks < 2; ++ks)
            qa[ks] = *(const bf16x8*)(qp + (size_t)(q0 + w * 16 + col) * 64
                                      + ks * 32 + quad * 8);

        float mrow[4], lrow[4], bi[4];
        f32x4 of[4] = {};
        const int gi0 = q0 + w * 16 + quad * 4;
#pragma unroll
        for (int r = 0; r < 4; ++r) {
            mrow[r] = NEG_BIG; lrow[r] = 0.f;
            bi[r] = nslope * (float)(gi0 + r);
        }

        // prologue: stage kv-tile 0 into buffer 0 (1024 16B-chunks each)
        {
#pragma unroll
            for (int i = 0; i < 2; ++i) {
                int c = i * 512 + t;
                int row = c >> 3, j8 = (c & 7) ^ (row & 7);
                stage16(kp + (size_t)row * 64 + j8 * 8, Kbuf[0] + (i * 512 + w * 64) * 8);
            }
#pragma unroll
            for (int i = 0; i < 2; ++i) {
                int c = i * 512 + t;
                int d = c >> 4, j8 = (c & 15) ^ (d & 7);
                stage16(vtp + (size_t)d * 2048 + j8 * 8, Vbuf[0] + (i * 512 + w * 64) * 8);
            }
        }
        __syncthreads();

        for (int kvt = 0; kvt <= qt; ++kvt) {
            const int kv0 = kvt * 128;
            const bf16* Kb = Kbuf[kvt & 1];
            const bf16* Vb = Vbuf[kvt & 1];

            // prefetch next tile into the other buffer (async; drained by the
            // end-of-iteration barrier)
            if (kvt < qt) {
                bf16* Kn = Kbuf[(kvt & 1) ^ 1];
                bf16* Vn = Vbuf[(kvt & 1) ^ 1];
                const int nv0 = kv0 + 128;
#pragma unroll
                for (int i = 0; i < 2; ++i) {
                    int c = i * 512 + t;
                    int row = c >> 3, j8 = (c & 7) ^ (row & 7);
                    stage16(kp + (size_t)(nv0 + row) * 64 + j8 * 8, Kn + (i * 512 + w * 64) * 8);
                }
#pragma unroll
                for (int i = 0; i < 2; ++i) {
                    int c = i * 512 + t;
                    int d = c >> 4, j8 = (c & 15) ^ (d & 7);
                    stage16(vtp + (size_t)d * 2048 + nv0 + j8 * 8, Vn + (i * 512 + w * 64) * 8);
                }
            }

            // S = Q K^T  (swizzled K reads: chunk = (quad + 4*ks) ^ (row&7))
            f32x4 sc[8];
#pragma unroll
            for (int nj = 0; nj < 8; ++nj) {
                const int row = nj * 16 + col;
                const bf16* kb = Kb + row * 64;
                const int rx = row & 7;
                bf16x8 k0f = *(const bf16x8*)(kb + (quad ^ rx) * 8);
                bf16x8 k1f = *(const bf16x8*)(kb + ((quad + 4) ^ rx) * 8);
                f32x4 z = {};
                z = __builtin_amdgcn_mfma_f32_16x16x32_bf16(qa[0], k0f, z, 0, 0, 0);
                z = __builtin_amdgcn_mfma_f32_16x16x32_bf16(qa[1], k1f, z, 0, 0, 0);
                sc[nj] = z;
            }

            // softmax (exp2-domain, DPP reduces, hoisted ALiBi)
            const bool diag = (kvt == qt);
            float bj[8];
#pragma unroll
            for (int nj = 0; nj < 8; ++nj)
                bj[nj] = nslope * (float)(kv0 + nj * 16 + col);

#pragma unroll
            for (int r = 0; r < 4; ++r) {
#pragma unroll
                for (int nj = 0; nj < 8; ++nj)
                    sc[nj][r] += bi[r] - bj[nj];
                if (diag) {
                    const int gi = gi0 + r;
#pragma unroll
                    for (int nj = 0; nj < 8; ++nj)
                        if (kv0 + nj * 16 + col > gi) sc[nj][r] = NEG_BIG;
                }
                float mx = sc[0][r];
#pragma unroll
                for (int nj = 1; nj < 8; ++nj) mx = fmaxf(mx, sc[nj][r]);
                mx = red16_max(mx);
                const float mo = mrow[r];
                const float mn = fmaxf(mo, mx);
                const float alpha = EXP2F(mo - mn);
                float rs = 0.f;
#pragma unroll
                for (int nj = 0; nj < 8; ++nj) {
                    float p = EXP2F(sc[nj][r] - mn);
                    sc[nj][r] = p;
                    rs += p;
                }
                rs = red16_sum(rs);
                mrow[r] = mn;
                lrow[r] = lrow[r] * alpha + rs;
#pragma unroll
                for (int jd = 0; jd < 4; ++jd) of[jd][r] *= alpha;
            }

            // P: C/D -> A-operand layout via private per-wave LDS region
            // (no barrier needed: only this wave writes & reads Pw)
#pragma unroll
            for (int nj = 0; nj < 8; ++nj)
#pragma unroll
                for (int r = 0; r < 4; ++r)
                    Pw[(quad * 4 + r) * 136 + nj * 16 + col] = (bf16)sc[nj][r];

            // O += P V  (swizzled V reads: chunk = (kk*4+quad) ^ (d&7))
#pragma unroll
            for (int kk = 0; kk < 4; ++kk) {
                bf16x8 pa = *(const bf16x8*)(Pw + col * 136 + kk * 32 + quad * 8);
#pragma unroll
                for (int jd = 0; jd < 4; ++jd) {
                    const int rd = jd * 16 + col;
                    bf16x8 vbf = *(const bf16x8*)(Vb + rd * 128 + (((kk * 4 + quad) ^ (rd & 7)) * 8));
                    of[jd] = __builtin_amdgcn_mfma_f32_16x16x32_bf16(pa, vbf, of[jd], 0, 0, 0);
                }
            }

            // ONE barrier: (a) everyone done reading Kb/Vb before next-iter
            // overwrite, (b) vmcnt drain -> prefetched tile visible next iter.
            __syncthreads();
        }

        // normalize + write this q-tile's attn output (bf16) to [B,S,E]
#pragma unroll
        for (int r = 0; r < 4; ++r) {
            const int s = q0 + w * 16 + quad * 4 + r;
            const float inv_l = 1.f / lrow[r];
#pragma unroll
            for (int jd = 0; jd < 4; ++jd) {
                const int e = h * 64 + jd * 16 + col;
                O[((size_t)(b * 2048 + s)) * 1024 + e] = (bf16)(of[jd][r] * inv_l);
            }
        }
    }
}

// ---------------------------------------------------------------------------
// Output projection (R7-proven): A bf16 via stage16; Wo f32 via cvt8.
// ---------------------------------------------------------------------------
__global__ __launch_bounds__(256) void out_gemm(
    const bf16* __restrict__ A, const float* __restrict__ W,
    const float* __restrict__ bias, float* __restrict__ out)
{
    __shared__ alignas(16) bf16 As[128 * 32];
    __shared__ alignas(16) bf16 Bs[128 * 32];

    const int t    = threadIdx.x;
    const int lane = t & 63, w = t >> 6;
    const int quad = lane >> 4, col = lane & 15;
    const int n0 = blockIdx.x * 128;
    const int m0 = blockIdx.y * 128;
    const int K  = 1024;
    const int wm = (w >> 1) * 64, wn = (w & 1) * 64;
    const int r0 = t >> 2, c8 = (t & 3) * 8;
    f32x4 acc[4][4] = {};

    for (int k0 = 0; k0 < K; k0 += 32) {
        bf16x8 bx0 = cvt8(W + (size_t)(n0 + r0)      * K + k0 + c8);
        bf16x8 bx1 = cvt8(W + (size_t)(n0 + 64 + r0) * K + k0 + c8);
        __syncthreads();
#pragma unroll
        for (int i = 0; i < 2; ++i) {
            int c = i * 256 + t;
            stage16(A + (size_t)(m0 + (c >> 2)) * K + k0 + (c & 3) * 8,
                    As + (i * 256 + w * 64) * 8);
        }
        *(bf16x8*)(Bs + r0 * 32 + c8)        = bx0;
        *(bf16x8*)(Bs + (64 + r0) * 32 + c8) = bx1;
        __syncthreads();

        bf16x8 a[4], b[4];
#pragma unroll
        for (int i = 0; i < 4; ++i)
            a[i] = *(const bf16x8*)(As + (wm + i * 16 + col) * 32 + quad * 8);
#pragma unroll
        for (int j = 0; j < 4; ++j)
            b[j] = *(const bf16x8*)(Bs + (wn + j * 16 + col) * 32 + quad * 8);
#pragma unroll
        for (int i = 0; i < 4; ++i)
#pragma unroll
            for (int j = 0; j < 4; ++j)
                acc[i][j] = __builtin_amdgcn_mfma_f32_16x16x32_bf16(a[i], b[j], acc[i][j], 0, 0, 0);
    }

#pragma unroll
    for (int i = 0; i < 4; ++i) {
        const int mbase = m0 + wm + i * 16 + quad * 4;
#pragma unroll
        for (int j = 0; j < 4; ++j) {
            const int n = n0 + wn + j * 16 + col;
            const float bb = bias[n];
#pragma unroll
            for (int r = 0; r < 4; ++r)
                out[(size_t)(mbase + r) * 1024 + n] = acc[i][j][r] + bb;
        }
    }
}

extern "C" void kernel_launch(void* const* d_in, const int* in_sizes, int n_in,
                              void* d_out, int out_size, void* d_ws, size_t ws_size,
                              hipStream_t stream) {
    const float* x  = (const float*)d_in[0];
    const float* Wq = (const float*)d_in[1];
    const float* bq = (const float*)d_in[2];
    const float* Wk = (const float*)d_in[3];
    const float* bk = (const float*)d_in[4];
    const float* Wv = (const float*)d_in[5];
    const float* bv = (const float*)d_in[6];
    const float* Wo = (const float*)d_in[7];
    const float* bo = (const float*)d_in[8];
    float* out = (float*)d_out;

    // ws (32 MB, proven): [xb | q | k | v^T] bf16; attn output aliases xb.
    bf16* xb  = (bf16*)d_ws;
    bf16* qws = xb  + 4194304;
    bf16* kws = qws + 4194304;
    bf16* vws = kws + 4194304;
    bf16* aws = xb;

    // d_out scratch: bf16 Wq|Wk|Wv (6 MB); dead before out_gemm writes.
    bf16* wb = (bf16*)d_out;

    conv_all<<<dim3(3584), 256, 0, stream>>>(x, Wq, Wk, Wv, xb, wb);
    qkv_gemm<<<dim3(24, 32), 256, 0, stream>>>(xb, wb, bq, bk, bv, qws, kws, vws);
    attn_kernel<<<dim3(256), 512, 0, stream>>>(qws, kws, vws, aws);
    out_gemm<<<dim3(8, 32), 256, 0, stream>>>(aws, Wo, bo, out);
}